// Round 1
// baseline (372.209 us; speedup 1.0000x reference)
//
#include <hip/hip_runtime.h>

#define BS   8192
#define DIM  1024
#define TINV 10.0f    // 1 / TEMPERATURE
#define MARGIN 1.0f   // max(0.01, 1.0 - 0.1*0.0)

#define BM  128
#define BN  128
#define BKB 128       // fp8 K-bytes per staging iteration (2 x 32x32x64 MFMA k-steps)

// fp8 values are the normalized elements scaled by 16 -> dot = 256 * cos
#define QSCALE   16.0f
#define INV_QSQ  (1.0f / 256.0f)

typedef __attribute__((ext_vector_type(4)))  float f32x4;
typedef __attribute__((ext_vector_type(16))) float f32x16;
typedef __attribute__((ext_vector_type(4)))  int   int4v;
typedef __attribute__((ext_vector_type(8)))  int   int8v;

// ---------------- Kernel 1: L2-normalize rows, emit fp8(e4m3,x16) + posdist -
// (unchanged from R10 — one wave per row, pure shfl reduction)
__global__ __launch_bounds__(256) void normalize_kernel(
    const float* __restrict__ feat,
    unsigned char* __restrict__ Afp8,
    unsigned char* __restrict__ Nfp8,
    float* __restrict__ posdist)
{
    const int lane = threadIdx.x & 63;
    const int row  = blockIdx.x * 4 + (threadIdx.x >> 6);   // wave = row

    const float4* fo = (const float4*)(feat + (size_t)row * DIM);
    const float4* fp = (const float4*)(feat + (size_t)(BS + row) * DIM);
    const float4* fn = (const float4*)(feat + (size_t)(2 * BS + row) * DIM);

    float4 o[4], p[4], n[4];
    #pragma unroll
    for (int k = 0; k < 4; k++) {
        o[k] = fo[lane + 64 * k];
        p[k] = fp[lane + 64 * k];
        n[k] = fn[lane + 64 * k];
    }

    float so = 0.f, sp = 0.f, sn = 0.f;
    #pragma unroll
    for (int k = 0; k < 4; k++) {
        so += o[k].x*o[k].x + o[k].y*o[k].y + o[k].z*o[k].z + o[k].w*o[k].w;
        sp += p[k].x*p[k].x + p[k].y*p[k].y + p[k].z*p[k].z + p[k].w*p[k].w;
        sn += n[k].x*n[k].x + n[k].y*n[k].y + n[k].z*n[k].z + n[k].w*n[k].w;
    }
    #pragma unroll
    for (int off = 1; off < 64; off <<= 1) {
        so += __shfl_xor(so, off);
        sp += __shfl_xor(sp, off);
        sn += __shfl_xor(sn, off);
    }

    const float io  = 1.0f / fmaxf(sqrtf(so), 1e-12f);
    const float ip  = 1.0f / fmaxf(sqrtf(sp), 1e-12f);
    const float in_ = 1.0f / fmaxf(sqrtf(sn), 1e-12f);

    int* Ar = (int*)(Afp8 + (size_t)row * DIM);
    int* Nr = (int*)(Nfp8 + (size_t)row * DIM);

    float d = 0.f;
    #pragma unroll
    for (int k = 0; k < 4; k++) {
        float ax = o[k].x*io, ay = o[k].y*io, az = o[k].z*io, aw = o[k].w*io;
        float nx = n[k].x*in_, ny = n[k].y*in_, nz = n[k].z*in_, nw = n[k].w*in_;
        int pa = __builtin_amdgcn_cvt_pk_fp8_f32(ax*QSCALE, ay*QSCALE, 0, false);
        pa     = __builtin_amdgcn_cvt_pk_fp8_f32(az*QSCALE, aw*QSCALE, pa, true);
        int pn = __builtin_amdgcn_cvt_pk_fp8_f32(nx*QSCALE, ny*QSCALE, 0, false);
        pn     = __builtin_amdgcn_cvt_pk_fp8_f32(nz*QSCALE, nw*QSCALE, pn, true);
        Ar[lane + 64 * k] = pa;      // coalesced 4B stores
        Nr[lane + 64 * k] = pn;
        float dx = ax - p[k].x*ip, dy = ay - p[k].y*ip;
        float dz = az - p[k].z*ip, dw = aw - p[k].w*ip;
        d += dx*dx + dy*dy + dz*dz + dw*dw;
    }
    #pragma unroll
    for (int off = 1; off < 64; off <<= 1) d += __shfl_xor(d, off);
    if (lane == 0) posdist[row] = d * TINV;
}

// Load one 32B fragment from swizzled LDS: lo chunk at `off`, hi at off^16
// (chunk parity: c0 even, so (c0+1)^x == (c0^x)^1). Union avoids repack.
__device__ __forceinline__ int8v ld_frag(const unsigned char* __restrict__ p,
                                         int off) {
    union { int8v v; struct { int4v lo, hi; } s; } u;
    u.s.lo = *(const int4v*)(p + off);
    u.s.hi = *(const int4v*)(p + (off ^ 16));
    return u.v;
}

// ---------------- Kernel 2: MX-fp8 32x32x64 MFMA max-GEMM (R11) -------------
// R11: switch 16x16x128 -> 32x32x64, wave tile 32x64 -> 64x64, block 128x64 ->
// 128x128. Rationale: R9/R10 was LDS-read-BW-bound (43.7 FLOP/LDS-byte ->
// 3.15 GB of ds_read @ ~69 TB/s ~= 46 us > 29.5 us MFMA floor; MfmaUtil 26%).
// 32x32x64 at a 64x64 wave tile doubles FLOP per LDS byte (64 FLOP/B) ->
// ~2.1 GB ds_read ~= 30 us, balanced with the MFMA pipe.
// A-operand layout (mirrors proven 16x16x128 pattern): row = lane&31,
// k = (lane>>5)*32 + r.  C/D: col = lane&31, row = (reg&3)+8*(reg>>2)+4*(lane>>5).
__global__ __launch_bounds__(256) void maxgemm_kernel(
    const unsigned char* __restrict__ Afp8,
    const unsigned char* __restrict__ Nfp8,
    float* __restrict__ partial)   // [BS][128] row-major
{
    __shared__ unsigned char As[BM * BKB];   // 16 KiB
    __shared__ unsigned char Bs[BN * BKB];   // 16 KiB

    const int tid  = threadIdx.x;
    const int lane = tid & 63;
    const int w    = tid >> 6;      // wave 0..3
    const int wr   = w >> 1;        // wave-row: 64 output rows
    const int wc   = w & 1;         // wave-col: 64 output cols
    const int rowBase = blockIdx.y * BM;
    const int colBase = blockIdx.x * BN;

    // staging: each wave stages 32 rows of A and 32 rows of B (4 slabs of 8)
    const int lrow = lane >> 3;                      // 0..7: row in 8-row slab
    const int gcol = ((lane & 7) ^ lrow) * 16;       // pre-swizzled global chunk

    const unsigned char* Ag = Afp8 + (size_t)rowBase * DIM;
    const unsigned char* Bg = Nfp8 + (size_t)colBase * DIM;

    // fragment read addressing
    const int frow = lane & 31;          // row within a 32-row fragment
    const int r7   = frow & 7;           // swizzle key (rows differ by mult of 32)
    const int q    = (lane >> 5) * 2;    // first 16B chunk of this lane's k-seg
    const int a0row = wr * 64 + frow;
    const int b0row = wc * 64 + frow;

    f32x16 acc[2][2];
    #pragma unroll
    for (int i = 0; i < 2; i++)
        #pragma unroll
        for (int j = 0; j < 2; j++)
            #pragma unroll
            for (int r = 0; r < 16; r++)
                acc[i][j][r] = 0.f;

    for (int k0 = 0; k0 < DIM; k0 += BKB) {
        __syncthreads();  // prior iter's LDS reads done
        #pragma unroll
        for (int c = 0; c < 4; c++) {               // A: 4 slabs of 8 rows/wave
            const int r0 = w * 32 + c * 8;
            __builtin_amdgcn_global_load_lds(
                (const __attribute__((address_space(1))) void*)
                    (Ag + (size_t)(r0 + lrow) * DIM + k0 + gcol),
                (__attribute__((address_space(3))) void*)(As + r0 * BKB),
                16, 0, 0);
        }
        #pragma unroll
        for (int c = 0; c < 4; c++) {               // B: 4 slabs of 8 rows/wave
            const int r0 = w * 32 + c * 8;
            __builtin_amdgcn_global_load_lds(
                (const __attribute__((address_space(1))) void*)
                    (Bg + (size_t)(r0 + lrow) * DIM + k0 + gcol),
                (__attribute__((address_space(3))) void*)(Bs + r0 * BKB),
                16, 0, 0);
        }
        __syncthreads();  // vmcnt drained by barrier semantics

        #pragma unroll
        for (int ks = 0; ks < 2; ks++) {            // two 64B k-steps per stage
            const int sc = ((ks * 4 + q) ^ r7) << 4;
            const int8v a0 = ld_frag(As, a0row * BKB + sc);
            const int8v a1 = ld_frag(As, (a0row + 32) * BKB + sc);
            const int8v b0 = ld_frag(Bs, b0row * BKB + sc);
            const int8v b1 = ld_frag(Bs, (b0row + 32) * BKB + sc);
            acc[0][0] = __builtin_amdgcn_mfma_scale_f32_32x32x64_f8f6f4(
                a0, b0, acc[0][0], 0, 0, 0, 0x7F7F7F7F, 0, 0x7F7F7F7F);
            acc[0][1] = __builtin_amdgcn_mfma_scale_f32_32x32x64_f8f6f4(
                a0, b1, acc[0][1], 0, 0, 0, 0x7F7F7F7F, 0, 0x7F7F7F7F);
            acc[1][0] = __builtin_amdgcn_mfma_scale_f32_32x32x64_f8f6f4(
                a1, b0, acc[1][0], 0, 0, 0, 0x7F7F7F7F, 0, 0x7F7F7F7F);
            acc[1][1] = __builtin_amdgcn_mfma_scale_f32_32x32x64_f8f6f4(
                a1, b1, acc[1][1], 0, 0, 0, 0x7F7F7F7F, 0, 0x7F7F7F7F);
        }
    }

    // Epilogue: per-row max over this wave's 64 columns (j-frags + lane&31).
    // C/D layout: col = lane&31, row = (reg&3) + 8*(reg>>2) + 4*(lane>>5).
    const int stripe = blockIdx.x * 2 + wc;          // 64-col stripe index
    #pragma unroll
    for (int i = 0; i < 2; i++) {
        #pragma unroll
        for (int r = 0; r < 16; r++) {
            float v = fmaxf(acc[i][0][r], acc[i][1][r]);
            v = fmaxf(v, __shfl_xor(v, 1));
            v = fmaxf(v, __shfl_xor(v, 2));
            v = fmaxf(v, __shfl_xor(v, 4));
            v = fmaxf(v, __shfl_xor(v, 8));
            v = fmaxf(v, __shfl_xor(v, 16));
            if ((lane & 31) == 0) {
                const int row = rowBase + wr * 64 + i * 32 +
                                (r & 3) + 8 * (r >> 2) + 4 * (lane >> 5);
                partial[(size_t)row * 128 + stripe] = v;   // = 256 * cos
            }
        }
    }
}

// ---------------- Kernel 3: stripe-max -> loss terms -> per-block partials --
__global__ __launch_bounds__(256) void reduce_kernel(
    const float* __restrict__ partial,
    const float* __restrict__ posdist,
    float* __restrict__ blockpart)   // [64][3]
{
    const int tid  = threadIdx.x;
    const int lane = tid & 63;
    const int w    = tid >> 6;
    __shared__ float red[4][3];

    float sloss = 0.f, spos = 0.f, shard = 0.f;

    #pragma unroll 4
    for (int i = 0; i < 32; i++) {
        const int row = blockIdx.x * 128 + w * 32 + i;
        float v = fmaxf(partial[(size_t)row * 128 + lane],
                        partial[(size_t)row * 128 + 64 + lane]);
        #pragma unroll
        for (int off = 1; off < 64; off <<= 1) v = fmaxf(v, __shfl_xor(v, off));
        if (lane == 0) {
            // v = 256*cos  ->  hard = (2 - 2*cos)/T = (2 - v/128)*TINV
            const float hard = (2.0f - 2.0f * v * INV_QSQ) * TINV;
            const float pos  = posdist[row];
            sloss += fmaxf(MARGIN + pos - hard, 0.0f);
            spos  += pos;
            shard += hard;
        }
    }
    if (lane == 0) { red[w][0] = sloss; red[w][1] = spos; red[w][2] = shard; }
    __syncthreads();
    if (tid == 0) {
        #pragma unroll
        for (int k = 0; k < 3; k++)
            blockpart[blockIdx.x * 3 + k] =
                red[0][k] + red[1][k] + red[2][k] + red[3][k];
    }
}

// ---------------- Kernel 4: finalize means (one wave, no atomics) -----------
__global__ __launch_bounds__(64) void finalize_kernel(
    const float* __restrict__ blockpart,
    float* __restrict__ out)
{
    const int lane = threadIdx.x;
    float a = blockpart[lane * 3 + 0];
    float b = blockpart[lane * 3 + 1];
    float c = blockpart[lane * 3 + 2];
    #pragma unroll
    for (int off = 1; off < 64; off <<= 1) {
        a += __shfl_xor(a, off);
        b += __shfl_xor(b, off);
        c += __shfl_xor(c, off);
    }
    if (lane == 0) {
        const float inv = 1.0f / (float)BS;
        out[0] = a * inv;
        out[1] = b * inv;
        out[2] = c * inv;
    }
}

extern "C" void kernel_launch(void* const* d_in, const int* in_sizes, int n_in,
                              void* d_out, int out_size, void* d_ws, size_t ws_size,
                              hipStream_t stream) {
    const float* feat = (const float*)d_in[0];
    char* ws = (char*)d_ws;

    // ws layout: Afp8 8MiB | Nfp8 8MiB | partial 4MiB | posdist 32KiB | blockpart
    unsigned char* Afp8      = (unsigned char*)ws;
    unsigned char* Nfp8      = (unsigned char*)(ws + ((size_t)8 << 20));
    float*         partial   = (float*)(ws + ((size_t)16 << 20));
    float*         posdist   = (float*)(ws + ((size_t)20 << 20));
    float*         blockpart = (float*)(ws + ((size_t)20 << 20) + 32768);

    normalize_kernel<<<BS / 4, 256, 0, stream>>>(feat, Afp8, Nfp8, posdist);

    maxgemm_kernel<<<dim3(BS / BN, BS / BM), 256, 0, stream>>>(Afp8, Nfp8, partial);

    reduce_kernel<<<64, 256, 0, stream>>>(partial, posdist, blockpart);
    finalize_kernel<<<1, 64, 0, stream>>>(blockpart, (float*)d_out);
}

// Round 2
// 264.267 us; speedup vs baseline: 1.4085x; 1.4085x over previous
//
#include <hip/hip_runtime.h>

#define BS   8192
#define DIM  1024
#define TINV 10.0f    // 1 / TEMPERATURE
#define MARGIN 1.0f   // max(0.01, 1.0 - 0.1*0.0)

#define BM  128
#define BN  64
#define BKB 128       // fp8 K-bytes per staging iteration (16x16x128 MFMA)

// fp8 values are the normalized elements scaled by 16 -> dot = 256 * cos
#define QSCALE   16.0f
#define INV_QSQ  (1.0f / 256.0f)

typedef __attribute__((ext_vector_type(4))) float f32x4;
typedef __attribute__((ext_vector_type(4))) int   int4v;
typedef __attribute__((ext_vector_type(8))) int   int8v;

// ---------------- Kernel 1: L2-normalize rows, emit fp8(e4m3,x16) + posdist -
// (unchanged from R10 — one wave per row, pure shfl reduction)
__global__ __launch_bounds__(256) void normalize_kernel(
    const float* __restrict__ feat,
    unsigned char* __restrict__ Afp8,
    unsigned char* __restrict__ Nfp8,
    float* __restrict__ posdist)
{
    const int lane = threadIdx.x & 63;
    const int row  = blockIdx.x * 4 + (threadIdx.x >> 6);   // wave = row

    const float4* fo = (const float4*)(feat + (size_t)row * DIM);
    const float4* fp = (const float4*)(feat + (size_t)(BS + row) * DIM);
    const float4* fn = (const float4*)(feat + (size_t)(2 * BS + row) * DIM);

    float4 o[4], p[4], n[4];
    #pragma unroll
    for (int k = 0; k < 4; k++) {
        o[k] = fo[lane + 64 * k];
        p[k] = fp[lane + 64 * k];
        n[k] = fn[lane + 64 * k];
    }

    float so = 0.f, sp = 0.f, sn = 0.f;
    #pragma unroll
    for (int k = 0; k < 4; k++) {
        so += o[k].x*o[k].x + o[k].y*o[k].y + o[k].z*o[k].z + o[k].w*o[k].w;
        sp += p[k].x*p[k].x + p[k].y*p[k].y + p[k].z*p[k].z + p[k].w*p[k].w;
        sn += n[k].x*n[k].x + n[k].y*n[k].y + n[k].z*n[k].z + n[k].w*n[k].w;
    }
    #pragma unroll
    for (int off = 1; off < 64; off <<= 1) {
        so += __shfl_xor(so, off);
        sp += __shfl_xor(sp, off);
        sn += __shfl_xor(sn, off);
    }

    const float io  = 1.0f / fmaxf(sqrtf(so), 1e-12f);
    const float ip  = 1.0f / fmaxf(sqrtf(sp), 1e-12f);
    const float in_ = 1.0f / fmaxf(sqrtf(sn), 1e-12f);

    int* Ar = (int*)(Afp8 + (size_t)row * DIM);
    int* Nr = (int*)(Nfp8 + (size_t)row * DIM);

    float d = 0.f;
    #pragma unroll
    for (int k = 0; k < 4; k++) {
        float ax = o[k].x*io, ay = o[k].y*io, az = o[k].z*io, aw = o[k].w*io;
        float nx = n[k].x*in_, ny = n[k].y*in_, nz = n[k].z*in_, nw = n[k].w*in_;
        int pa = __builtin_amdgcn_cvt_pk_fp8_f32(ax*QSCALE, ay*QSCALE, 0, false);
        pa     = __builtin_amdgcn_cvt_pk_fp8_f32(az*QSCALE, aw*QSCALE, pa, true);
        int pn = __builtin_amdgcn_cvt_pk_fp8_f32(nx*QSCALE, ny*QSCALE, 0, false);
        pn     = __builtin_amdgcn_cvt_pk_fp8_f32(nz*QSCALE, nw*QSCALE, pn, true);
        Ar[lane + 64 * k] = pa;      // coalesced 4B stores
        Nr[lane + 64 * k] = pn;
        float dx = ax - p[k].x*ip, dy = ay - p[k].y*ip;
        float dz = az - p[k].z*ip, dw = aw - p[k].w*ip;
        d += dx*dx + dy*dy + dz*dz + dw*dw;
    }
    #pragma unroll
    for (int off = 1; off < 64; off <<= 1) d += __shfl_xor(d, off);
    if (lane == 0) posdist[row] = d * TINV;
}

// Load one 32B fragment from swizzled LDS: lo chunk at `off`, hi at off^16
// (chunk parity: (q2+1)^x == (q2^x)^1 for even q2). Union avoids repack.
__device__ __forceinline__ int8v ld_frag(const unsigned char* __restrict__ p,
                                         int off) {
    union { int8v v; struct { int4v lo, hi; } s; } u;
    u.s.lo = *(const int4v*)(p + off);
    u.s.hi = *(const int4v*)(p + (off ^ 16));
    return u.v;
}

// ---------------- Kernel 2: MX-fp8 16x16x128 MFMA max-GEMM (R12) ------------
// R12 = R9 structure (108 us, VGPR 80) + LDS double-buffer 2-phase prefetch.
// R11 post-mortem: 32x32x64 halved LDS traffic but acc=64 VGPR -> 228 total,
// occupancy 11.6%, 216 us. Reverted. R9's stall is the serial
// stage -> vmcnt(0)+barrier -> compute per K-step; T3-minimum-2-phase
// overlaps tile t+1's global_load_lds with tile t's ds_read+MFMA, ONE
// __syncthreads per K-step (its vmcnt(0) drain lands after compute).
// Bank-conflict note: 4.0 extra cyc per b128 read in BOTH R9 and R11
// swizzles -> b128 intrinsic floor (m134), not fixable by layout.
__global__ __launch_bounds__(256) void maxgemm_kernel(
    const unsigned char* __restrict__ Afp8,
    const unsigned char* __restrict__ Nfp8,
    float* __restrict__ partial)   // [BS][128] row-major
{
    __shared__ unsigned char As[2][BM * BKB];   // 2 x 16 KiB
    __shared__ unsigned char Bs[2][BN * BKB];   // 2 x  8 KiB

    const int tid  = threadIdx.x;
    const int lane = tid & 63;
    const int w    = tid >> 6;
    const int rowBase = blockIdx.y * BM;
    const int colBase = blockIdx.x * BN;

    const int lrow = lane >> 3;                      // 0..7: row in 8-row slab
    const int gcol = ((lane & 7) ^ lrow) * 16;       // swizzled 16B chunk (bytes)

    const unsigned char* Ag = Afp8 + (size_t)rowBase * DIM;
    const unsigned char* Bg = Nfp8 + (size_t)colBase * DIM;

    const int q2   = (lane >> 4) * 2;                // first 16B chunk of quad
    const int arow = w * 32 + (lane & 15);           // + i*16, i=0..1
    const int brow = (lane & 15);                    // + j*16, j=0..3
    const int aoff = arow * BKB + ((q2 ^ (arow & 7)) << 4);
    const int boff = brow * BKB + ((q2 ^ (brow & 7)) << 4);

    f32x4 acc[2][4];
    #pragma unroll
    for (int i = 0; i < 2; i++)
        #pragma unroll
        for (int j = 0; j < 4; j++)
            acc[i][j] = (f32x4){0.f, 0.f, 0.f, 0.f};

    // ---- prologue: stage tile 0 into buffer 0 ----
    #pragma unroll
    for (int c = 0; c < 4; c++) {
        const int r0 = (w * 4 + c) * 8;
        __builtin_amdgcn_global_load_lds(
            (const __attribute__((address_space(1))) void*)
                (Ag + (size_t)(r0 + lrow) * DIM + gcol),
            (__attribute__((address_space(3))) void*)(&As[0][r0 * BKB]),
            16, 0, 0);
    }
    #pragma unroll
    for (int s = 0; s < 2; s++) {
        const int r0 = (w * 2 + s) * 8;
        __builtin_amdgcn_global_load_lds(
            (const __attribute__((address_space(1))) void*)
                (Bg + (size_t)(r0 + lrow) * DIM + gcol),
            (__attribute__((address_space(3))) void*)(&Bs[0][r0 * BKB]),
            16, 0, 0);
    }
    __syncthreads();   // vmcnt(0) drained by barrier semantics

    int cur = 0;
    for (int k0 = 0; k0 < DIM; k0 += BKB, cur ^= 1) {
        const int k1 = k0 + BKB;
        if (k1 < DIM) {
            // ---- prefetch tile t+1 into the other buffer (overlaps compute)
            #pragma unroll
            for (int c = 0; c < 4; c++) {
                const int r0 = (w * 4 + c) * 8;
                __builtin_amdgcn_global_load_lds(
                    (const __attribute__((address_space(1))) void*)
                        (Ag + (size_t)(r0 + lrow) * DIM + k1 + gcol),
                    (__attribute__((address_space(3))) void*)(&As[cur ^ 1][r0 * BKB]),
                    16, 0, 0);
            }
            #pragma unroll
            for (int s = 0; s < 2; s++) {
                const int r0 = (w * 2 + s) * 8;
                __builtin_amdgcn_global_load_lds(
                    (const __attribute__((address_space(1))) void*)
                        (Bg + (size_t)(r0 + lrow) * DIM + k1 + gcol),
                    (__attribute__((address_space(3))) void*)(&Bs[cur ^ 1][r0 * BKB]),
                    16, 0, 0);
            }
        }

        // ---- compute tile t from buffer cur ----
        int8v bf[4];
        #pragma unroll
        for (int j = 0; j < 4; j++)
            bf[j] = ld_frag(&Bs[cur][0], boff + j * 16 * BKB);

        #pragma unroll
        for (int i = 0; i < 2; i++) {
            const int8v a = ld_frag(&As[cur][0], aoff + i * 16 * BKB);
            #pragma unroll
            for (int j = 0; j < 4; j++)
                acc[i][j] = __builtin_amdgcn_mfma_scale_f32_16x16x128_f8f6f4(
                    a, bf[j], acc[i][j],
                    0, 0,               // cbsz=FP8(e4m3), blgp=FP8(e4m3)
                    0, 0x7F7F7F7F,      // opselA, scaleA = 1.0
                    0, 0x7F7F7F7F);     // opselB, scaleB = 1.0
        }

        // one barrier per K-step: drains this iter's prefetch vmcnt AND
        // guarantees all waves finished reading buf[cur] before it is
        // overwritten next iteration.
        __syncthreads();
    }

    // Epilogue: per-row max over this block's 64 columns (all in this wave).
    // C/D layout (m89/m91): col = lane&15, row = (lane>>4)*4 + reg.
    const int stripe = blockIdx.x;
    #pragma unroll
    for (int i = 0; i < 2; i++) {
        #pragma unroll
        for (int r = 0; r < 4; r++) {
            float v = fmaxf(fmaxf(acc[i][0][r], acc[i][1][r]),
                            fmaxf(acc[i][2][r], acc[i][3][r]));
            v = fmaxf(v, __shfl_xor(v, 1));
            v = fmaxf(v, __shfl_xor(v, 2));
            v = fmaxf(v, __shfl_xor(v, 4));
            v = fmaxf(v, __shfl_xor(v, 8));
            if ((lane & 15) == 0) {
                const int row = rowBase + w * 32 + i * 16 + (lane >> 4) * 4 + r;
                partial[(size_t)row * 128 + stripe] = v;   // = 256 * cos
            }
        }
    }
}

// ---------------- Kernel 3: stripe-max -> loss terms -> per-block partials --
__global__ __launch_bounds__(256) void reduce_kernel(
    const float* __restrict__ partial,
    const float* __restrict__ posdist,
    float* __restrict__ blockpart)   // [64][3]
{
    const int tid  = threadIdx.x;
    const int lane = tid & 63;
    const int w    = tid >> 6;
    __shared__ float red[4][3];

    float sloss = 0.f, spos = 0.f, shard = 0.f;

    #pragma unroll 4
    for (int i = 0; i < 32; i++) {
        const int row = blockIdx.x * 128 + w * 32 + i;
        float v = fmaxf(partial[(size_t)row * 128 + lane],
                        partial[(size_t)row * 128 + 64 + lane]);
        #pragma unroll
        for (int off = 1; off < 64; off <<= 1) v = fmaxf(v, __shfl_xor(v, off));
        if (lane == 0) {
            // v = 256*cos  ->  hard = (2 - 2*cos)/T = (2 - v/128)*TINV
            const float hard = (2.0f - 2.0f * v * INV_QSQ) * TINV;
            const float pos  = posdist[row];
            sloss += fmaxf(MARGIN + pos - hard, 0.0f);
            spos  += pos;
            shard += hard;
        }
    }
    if (lane == 0) { red[w][0] = sloss; red[w][1] = spos; red[w][2] = shard; }
    __syncthreads();
    if (tid == 0) {
        #pragma unroll
        for (int k = 0; k < 3; k++)
            blockpart[blockIdx.x * 3 + k] =
                red[0][k] + red[1][k] + red[2][k] + red[3][k];
    }
}

// ---------------- Kernel 4: finalize means (one wave, no atomics) -----------
__global__ __launch_bounds__(64) void finalize_kernel(
    const float* __restrict__ blockpart,
    float* __restrict__ out)
{
    const int lane = threadIdx.x;
    float a = blockpart[lane * 3 + 0];
    float b = blockpart[lane * 3 + 1];
    float c = blockpart[lane * 3 + 2];
    #pragma unroll
    for (int off = 1; off < 64; off <<= 1) {
        a += __shfl_xor(a, off);
        b += __shfl_xor(b, off);
        c += __shfl_xor(c, off);
    }
    if (lane == 0) {
        const float inv = 1.0f / (float)BS;
        out[0] = a * inv;
        out[1] = b * inv;
        out[2] = c * inv;
    }
}

extern "C" void kernel_launch(void* const* d_in, const int* in_sizes, int n_in,
                              void* d_out, int out_size, void* d_ws, size_t ws_size,
                              hipStream_t stream) {
    const float* feat = (const float*)d_in[0];
    char* ws = (char*)d_ws;

    // ws layout: Afp8 8MiB | Nfp8 8MiB | partial 4MiB | posdist 32KiB | blockpart
    unsigned char* Afp8      = (unsigned char*)ws;
    unsigned char* Nfp8      = (unsigned char*)(ws + ((size_t)8 << 20));
    float*         partial   = (float*)(ws + ((size_t)16 << 20));
    float*         posdist   = (float*)(ws + ((size_t)20 << 20));
    float*         blockpart = (float*)(ws + ((size_t)20 << 20) + 32768);

    normalize_kernel<<<BS / 4, 256, 0, stream>>>(feat, Afp8, Nfp8, posdist);

    maxgemm_kernel<<<dim3(BS / BN, BS / BM), 256, 0, stream>>>(Afp8, Nfp8, partial);

    reduce_kernel<<<64, 256, 0, stream>>>(partial, posdist, blockpart);
    finalize_kernel<<<1, 64, 0, stream>>>(blockpart, (float*)d_out);
}